// Round 11
// baseline (350.109 us; speedup 1.0000x reference)
//
#include <hip/hip_runtime.h>
#include <math.h>

// 3-layer GAT, N=50000, E=800000 (+N self loops).
// L0 collapsed to 2-dim aggregation, fused into the L1 GEMM's A-staging phase
// (x1 reconstructed in-register from rank-2 agg + b0 + relu, split-bf16 MFMA).
// h1 stored fp16 permuted; L2 projection fused into edge1 epilogue.
// Softmax without max subtraction (shift-invariant; |e| << 88).
// CSR: memset(deg) -> prep(hist+W1conv+vs) -> scan(deg+1) -> finish -> scatter.

typedef __attribute__((ext_vector_type(8))) short s16x8;
typedef __attribute__((ext_vector_type(4))) float f32x4;
typedef unsigned short u16;

__device__ __forceinline__ float wred_sum(float v){
  #pragma unroll
  for (int m = 32; m > 0; m >>= 1) v += __shfl_xor(v, m, 64);
  return v;
}
__device__ __forceinline__ void wred_sum4(float4& v){
  #pragma unroll
  for (int m = 32; m > 0; m >>= 1){
    v.x += __shfl_xor(v.x, m, 64);
    v.y += __shfl_xor(v.y, m, 64);
    v.z += __shfl_xor(v.z, m, 64);
    v.w += __shfl_xor(v.w, m, 64);
  }
}
__device__ __forceinline__ u16 bf16_rne(float x){
  unsigned int u = __float_as_uint(x);
  unsigned int r = u + 0x7FFFu + ((u >> 16) & 1u);
  return (u16)(r >> 16);
}

// ---------------- prep: edge histogram + W1 hi/lo transpose-convert + vs(=W0@a0) ----------------
__global__ __launch_bounds__(256) void k_prep(const int* __restrict__ dst, int E, int* __restrict__ deg,
                                              const float* __restrict__ W1, u16* __restrict__ WhT,
                                              u16* __restrict__ WlT,
                                              const float* __restrict__ W0, const float* __restrict__ as0,
                                              const float* __restrict__ ad0, float* __restrict__ vs,
                                              int nhist){
  int b = blockIdx.x;
  if (b < nhist){
    int e = b * 256 + threadIdx.x;
    if (e < E) atomicAdd(&deg[dst[e]], 1);
  } else if (b < nhist + 256){
    int k = b - nhist, j = threadIdx.x;
    float w = W1[k * 256 + j];
    u16 h = bf16_rne(w);
    float hf = __uint_as_float(((unsigned int)h) << 16);
    WhT[j * 256 + k] = h;
    WlT[j * 256 + k] = bf16_rne(w - hf);
  } else {
    int t = threadIdx.x;
    if (t < 8){
      int j = t >> 2, h = t & 3;
      float ss = 0.f, dd = 0.f;
      #pragma unroll 8
      for (int o = 0; o < 64; o++){
        float w = W0[j * 256 + h * 64 + o];
        ss = fmaf(w, as0[h * 64 + o], ss);
        dd = fmaf(w, ad0[h * 64 + o], dd);
      }
      vs[j * 4 + h]     = ss;   // src proj
      vs[8 + j * 4 + h] = dd;   // dst proj
    }
  }
}

// ---------------- scan: local (2048/block, deg+1 for self loop) -> finish ----------------
__global__ __launch_bounds__(256) void k_scan_local(const int* __restrict__ deg, int* __restrict__ rowptr,
                                                    int* __restrict__ bsum, int N){
  __shared__ int sb[256];
  int t = threadIdx.x;
  int base = blockIdx.x * 2048 + t * 8;
  int d[8], s = 0;
  #pragma unroll
  for (int k = 0; k < 8; k++){
    d[k] = (base + k < N) ? (deg[base + k] + 1) : 0;
    s += d[k];
  }
  sb[t] = s;
  __syncthreads();
  for (int off = 1; off < 256; off <<= 1){
    int v = (t >= off) ? sb[t - off] : 0;
    __syncthreads();
    sb[t] += v;
    __syncthreads();
  }
  int run = (t == 0) ? 0 : sb[t - 1];
  #pragma unroll
  for (int k = 0; k < 8; k++){
    if (base + k < N) rowptr[base + k] = run;
    run += d[k];
  }
  if (t == 255) bsum[blockIdx.x] = sb[255];
}

__global__ __launch_bounds__(256) void k_finish(int* __restrict__ rowptr, const int* __restrict__ bsum,
                                                int* __restrict__ ssrc, int* __restrict__ cursor,
                                                int N, int nb){
  __shared__ int off_sh;
  int i = blockIdx.x * 256 + threadIdx.x;
  if (threadIdx.x == 0){
    int bk = blockIdx.x >> 3;     // 256-aligned range never crosses a 2048 boundary
    int s = 0;
    for (int k = 0; k < bk; k++) s += bsum[k];
    off_sh = s;
  }
  __syncthreads();
  if (i < N){
    int p = rowptr[i] + off_sh;
    rowptr[i] = p;
    ssrc[p] = i;          // self loop first in segment
    cursor[i] = p + 1;
  }
  if (i == 0){
    int s = 0;
    for (int k = 0; k < nb; k++) s += bsum[k];
    rowptr[N] = s;
  }
}

__global__ __launch_bounds__(256) void k_scatter(const int* __restrict__ src, const int* __restrict__ dst,
                                                 int E, int* cursor, int* ssrc){
  int e = blockIdx.x * 256 + threadIdx.x;
  if (e < E){ int p = atomicAdd(&cursor[dst[e]], 1); ssrc[p] = src[e]; }
}

// ---------------- fused L0-aggregation + L1 GEMM ----------------
// Phase 1 (per wave, register-only): for its 16 rows, 2-dim segment softmax over
// in-edges of x -> (g0,g1) per head; lane group (lane>>2)==i keeps node i's g.
// Phase 2: x1 row reconstructed as relu(g0*W0[0]+g1*W0[1]+b0), split hi/lo bf16,
// 3-MFMA GEMM vs W1; h1 -> fp16 permuted layout; ES1/ED1 epilogue.
// Block: 128 rows, 512 threads (8 waves x 16 rows). LDS 48 KB.
__global__ __launch_bounds__(512) void k_l1f(const float* __restrict__ X, const float* __restrict__ vs,
                                             const int* __restrict__ rowptr, const int* __restrict__ ssrc,
                                             const float* __restrict__ W0, const float* __restrict__ b0,
                                             const u16* __restrict__ WhT, const u16* __restrict__ WlT,
                                             const float* __restrict__ as_, const float* __restrict__ ad_,
                                             u16* __restrict__ Hh16, float* __restrict__ ES,
                                             float* __restrict__ ED, int N){
  __shared__ u16 Ah[128 * 32], Al[128 * 32];
  __shared__ u16 Bh[256 * 32], Bl[256 * 32];
  int t = threadIdx.x;
  int wv = t >> 6, lane = t & 63;
  int lr = lane & 15, lg = lane >> 4;
  int rb = blockIdx.x * 128;

  // ---- phase 1: L0 aggregation for this wave's 16 nodes (register-only) ----
  float4 va = ((const float4*)vs)[0], vb = ((const float4*)vs)[1];
  float4 vc = ((const float4*)vs)[2], vd = ((const float4*)vs)[3];
  float4 myga = make_float4(0.f,0.f,0.f,0.f), mygb = make_float4(0.f,0.f,0.f,0.f);
  for (int i = 0; i < 16; i++){
    int n = rb + wv * 16 + i;
    if (n >= N) break;
    int start = rowptr[n], deg = rowptr[n + 1] - start;
    float2 xn = ((const float2*)X)[n];
    float4 ed4;
    ed4.x = fmaf(xn.x, vc.x, xn.y * vd.x); ed4.y = fmaf(xn.x, vc.y, xn.y * vd.y);
    ed4.z = fmaf(xn.x, vc.z, xn.y * vd.z); ed4.w = fmaf(xn.x, vc.w, xn.y * vd.w);
    float4 den = make_float4(0.f,0.f,0.f,0.f);
    float4 a0  = make_float4(0.f,0.f,0.f,0.f);
    float4 a1  = make_float4(0.f,0.f,0.f,0.f);
    for (int idx = lane; idx < deg; idx += 64){
      int s = ssrc[start + idx];
      float2 xs = ((const float2*)X)[s];
      float4 e;
      e.x = fmaf(xs.x, va.x, fmaf(xs.y, vb.x, ed4.x));
      e.y = fmaf(xs.x, va.y, fmaf(xs.y, vb.y, ed4.y));
      e.z = fmaf(xs.x, va.z, fmaf(xs.y, vb.z, ed4.z));
      e.w = fmaf(xs.x, va.w, fmaf(xs.y, vb.w, ed4.w));
      e.x = fmaxf(e.x, 0.2f*e.x); e.y = fmaxf(e.y, 0.2f*e.y);
      e.z = fmaxf(e.z, 0.2f*e.z); e.w = fmaxf(e.w, 0.2f*e.w);
      float4 wt;
      wt.x = __expf(e.x); wt.y = __expf(e.y);
      wt.z = __expf(e.z); wt.w = __expf(e.w);
      den.x += wt.x; den.y += wt.y; den.z += wt.z; den.w += wt.w;
      a0.x = fmaf(wt.x, xs.x, a0.x); a0.y = fmaf(wt.y, xs.x, a0.y);
      a0.z = fmaf(wt.z, xs.x, a0.z); a0.w = fmaf(wt.w, xs.x, a0.w);
      a1.x = fmaf(wt.x, xs.y, a1.x); a1.y = fmaf(wt.y, xs.y, a1.y);
      a1.z = fmaf(wt.z, xs.y, a1.z); a1.w = fmaf(wt.w, xs.y, a1.w);
    }
    wred_sum4(den); wred_sum4(a0); wred_sum4(a1);
    float4 inv;
    inv.x = 1.f / (den.x + 1e-16f); inv.y = 1.f / (den.y + 1e-16f);
    inv.z = 1.f / (den.z + 1e-16f); inv.w = 1.f / (den.w + 1e-16f);
    float4 gA, gB;                              // {h0g0,h0g1,h1g0,h1g1}, {h2g0,...}
    gA.x = a0.x * inv.x; gA.y = a1.x * inv.x;
    gA.z = a0.y * inv.y; gA.w = a1.y * inv.y;
    gB.x = a0.z * inv.z; gB.y = a1.z * inv.z;
    gB.z = a0.w * inv.w; gB.w = a1.w * inv.w;
    if ((lane >> 2) == i){ myga = gA; mygb = gB; }
  }

  // ---- phase 2: split-bf16 MFMA GEMM ----
  f32x4 acc[16];
  #pragma unroll
  for (int c = 0; c < 16; c++) acc[c] = (f32x4){0.f, 0.f, 0.f, 0.f};

  int arow = t >> 2, aseg = t & 3;
  int agrow = rb + arow;

  for (int ks = 0; ks < 8; ks++){
    int k0 = ks * 32;
    __syncthreads();
    {
      int c0 = k0 + aseg * 8;
      int h = c0 >> 6;
      float g0 = (h==0)?myga.x:(h==1)?myga.z:(h==2)?mygb.x:mygb.z;
      float g1 = (h==0)?myga.y:(h==1)?myga.w:(h==2)?mygb.y:mygb.w;
      float4 w0a = *(const float4*)(W0 + c0);
      float4 w0b = *(const float4*)(W0 + c0 + 4);
      float4 w1a = *(const float4*)(W0 + 256 + c0);
      float4 w1b = *(const float4*)(W0 + 256 + c0 + 4);
      float4 bba = *(const float4*)(b0 + c0);
      float4 bbb = *(const float4*)(b0 + c0 + 4);
      float xv[8];
      xv[0] = fmaxf(fmaf(g0, w0a.x, fmaf(g1, w1a.x, bba.x)), 0.f);
      xv[1] = fmaxf(fmaf(g0, w0a.y, fmaf(g1, w1a.y, bba.y)), 0.f);
      xv[2] = fmaxf(fmaf(g0, w0a.z, fmaf(g1, w1a.z, bba.z)), 0.f);
      xv[3] = fmaxf(fmaf(g0, w0a.w, fmaf(g1, w1a.w, bba.w)), 0.f);
      xv[4] = fmaxf(fmaf(g0, w0b.x, fmaf(g1, w1b.x, bbb.x)), 0.f);
      xv[5] = fmaxf(fmaf(g0, w0b.y, fmaf(g1, w1b.y, bbb.y)), 0.f);
      xv[6] = fmaxf(fmaf(g0, w0b.z, fmaf(g1, w1b.z, bbb.z)), 0.f);
      xv[7] = fmaxf(fmaf(g0, w0b.w, fmaf(g1, w1b.w, bbb.w)), 0.f);
      if (agrow >= N){
        #pragma unroll
        for (int i = 0; i < 8; i++) xv[i] = 0.f;
      }
      union { u16 us[8]; uint4 v; } ph, pl;
      #pragma unroll
      for (int i = 0; i < 8; i++){
        u16 h16 = bf16_rne(xv[i]);
        float hf = __uint_as_float(((unsigned int)h16) << 16);
        ph.us[i] = h16;
        pl.us[i] = bf16_rne(xv[i] - hf);
      }
      *(uint4*)&Ah[arow * 32 + aseg * 8] = ph.v;
      *(uint4*)&Al[arow * 32 + aseg * 8] = pl.v;
    }
    #pragma unroll
    for (int i = 0; i < 2; i++){
      int chunk = i * 512 + t;          // 1024 chunks of 16B
      int j = chunk >> 2, seg = chunk & 3;
      *(uint4*)&Bh[j * 32 + seg * 8] = *(const uint4*)&WhT[j * 256 + k0 + seg * 8];
      *(uint4*)&Bl[j * 32 + seg * 8] = *(const uint4*)&WlT[j * 256 + k0 + seg * 8];
    }
    __syncthreads();
    s16x8 ah = *(const s16x8*)&Ah[(wv * 16 + lr) * 32 + lg * 8];
    s16x8 al = *(const s16x8*)&Al[(wv * 16 + lr) * 32 + lg * 8];
    #pragma unroll
    for (int c = 0; c < 16; c++){
      s16x8 bh = *(const s16x8*)&Bh[(c * 16 + lr) * 32 + lg * 8];
      s16x8 bl = *(const s16x8*)&Bl[(c * 16 + lr) * 32 + lg * 8];
      acc[c] = __builtin_amdgcn_mfma_f32_16x16x32_bf16(ah, bh, acc[c], 0, 0, 0);
      acc[c] = __builtin_amdgcn_mfma_f32_16x16x32_bf16(ah, bl, acc[c], 0, 0, 0);
      acc[c] = __builtin_amdgcn_mfma_f32_16x16x32_bf16(al, bh, acc[c], 0, 0, 0);
    }
  }

  // fp16 permuted write: row n, positions lr*16 + c (c=0..15) = cols c*16+lr
  #pragma unroll
  for (int q = 0; q < 4; q++){
    int n = rb + wv * 16 + lg * 4 + q;
    if (n < N){
      union { _Float16 h[16]; uint4 v[2]; } pk;
      #pragma unroll
      for (int c = 0; c < 16; c++) pk.h[c] = (_Float16)acc[c][q];
      uint4* dstp = (uint4*)(Hh16 + (size_t)n * 256 + lr * 16);
      dstp[0] = pk.v[0];
      dstp[1] = pk.v[1];
    }
  }
  // ES1/ED1 from full f32 acc
  float es_p[4][4], ed_p[4][4];
  #pragma unroll
  for (int h = 0; h < 4; h++)
    #pragma unroll
    for (int q = 0; q < 4; q++){ es_p[h][q] = 0.f; ed_p[h][q] = 0.f; }
  #pragma unroll
  for (int c = 0; c < 16; c++){
    float asv = as_[c * 16 + lr];
    float adv = ad_[c * 16 + lr];
    int h = c >> 2;
    #pragma unroll
    for (int q = 0; q < 4; q++){
      es_p[h][q] = fmaf(acc[c][q], asv, es_p[h][q]);
      ed_p[h][q] = fmaf(acc[c][q], adv, ed_p[h][q]);
    }
  }
  #pragma unroll
  for (int h = 0; h < 4; h++)
    #pragma unroll
    for (int q = 0; q < 4; q++){
      #pragma unroll
      for (int mk = 1; mk < 16; mk <<= 1){
        es_p[h][q] += __shfl_xor(es_p[h][q], mk, 64);
        ed_p[h][q] += __shfl_xor(ed_p[h][q], mk, 64);
      }
    }
  if (lr == 0){
    #pragma unroll
    for (int q = 0; q < 4; q++){
      int n = rb + wv * 16 + lg * 4 + q;
      if (n < N){
        #pragma unroll
        for (int h = 0; h < 4; h++){
          ES[n * 4 + h] = es_p[h][q];
          ED[n * 4 + h] = ed_p[h][q];
        }
      }
    }
  }
}

// ---------------- fp16 gather-aggregate helper (permuted layout, 8B/lane) ----------------
__device__ __forceinline__ void agg_rows16(const u16* __restrict__ Hh, const int* ssh, const float* wrow,
                                           int cl, int lane, float* acc){
  union Cv { uint2 u; _Float16 h[4]; };
  int j = 0;
  for (; j + 7 < cl; j += 8){
    Cv r0, r1, r2, r3, r4, r5, r6, r7;
    float w0=wrow[j],w1=wrow[j+1],w2=wrow[j+2],w3=wrow[j+3];
    float w4=wrow[j+4],w5=wrow[j+5],w6=wrow[j+6],w7=wrow[j+7];
    r0.u = *(const uint2*)(Hh + (size_t)ssh[j  ] * 256 + 4*lane);
    r1.u = *(const uint2*)(Hh + (size_t)ssh[j+1] * 256 + 4*lane);
    r2.u = *(const uint2*)(Hh + (size_t)ssh[j+2] * 256 + 4*lane);
    r3.u = *(const uint2*)(Hh + (size_t)ssh[j+3] * 256 + 4*lane);
    r4.u = *(const uint2*)(Hh + (size_t)ssh[j+4] * 256 + 4*lane);
    r5.u = *(const uint2*)(Hh + (size_t)ssh[j+5] * 256 + 4*lane);
    r6.u = *(const uint2*)(Hh + (size_t)ssh[j+6] * 256 + 4*lane);
    r7.u = *(const uint2*)(Hh + (size_t)ssh[j+7] * 256 + 4*lane);
    #pragma unroll
    for (int k = 0; k < 4; k++) acc[k] = fmaf(w0, (float)r0.h[k], acc[k]);
    #pragma unroll
    for (int k = 0; k < 4; k++) acc[k] = fmaf(w1, (float)r1.h[k], acc[k]);
    #pragma unroll
    for (int k = 0; k < 4; k++) acc[k] = fmaf(w2, (float)r2.h[k], acc[k]);
    #pragma unroll
    for (int k = 0; k < 4; k++) acc[k] = fmaf(w3, (float)r3.h[k], acc[k]);
    #pragma unroll
    for (int k = 0; k < 4; k++) acc[k] = fmaf(w4, (float)r4.h[k], acc[k]);
    #pragma unroll
    for (int k = 0; k < 4; k++) acc[k] = fmaf(w5, (float)r5.h[k], acc[k]);
    #pragma unroll
    for (int k = 0; k < 4; k++) acc[k] = fmaf(w6, (float)r6.h[k], acc[k]);
    #pragma unroll
    for (int k = 0; k < 4; k++) acc[k] = fmaf(w7, (float)r7.h[k], acc[k]);
  }
  for (; j + 3 < cl; j += 4){
    Cv r0, r1, r2, r3;
    float w0=wrow[j],w1=wrow[j+1],w2=wrow[j+2],w3=wrow[j+3];
    r0.u = *(const uint2*)(Hh + (size_t)ssh[j  ] * 256 + 4*lane);
    r1.u = *(const uint2*)(Hh + (size_t)ssh[j+1] * 256 + 4*lane);
    r2.u = *(const uint2*)(Hh + (size_t)ssh[j+2] * 256 + 4*lane);
    r3.u = *(const uint2*)(Hh + (size_t)ssh[j+3] * 256 + 4*lane);
    #pragma unroll
    for (int k = 0; k < 4; k++) acc[k] = fmaf(w0, (float)r0.h[k], acc[k]);
    #pragma unroll
    for (int k = 0; k < 4; k++) acc[k] = fmaf(w1, (float)r1.h[k], acc[k]);
    #pragma unroll
    for (int k = 0; k < 4; k++) acc[k] = fmaf(w2, (float)r2.h[k], acc[k]);
    #pragma unroll
    for (int k = 0; k < 4; k++) acc[k] = fmaf(w3, (float)r3.h[k], acc[k]);
  }
  for (; j < cl; ++j){
    Cv r0;
    float w0 = wrow[j];
    r0.u = *(const uint2*)(Hh + (size_t)ssh[j] * 256 + 4*lane);
    #pragma unroll
    for (int k = 0; k < 4; k++) acc[k] = fmaf(w0, (float)r0.h[k], acc[k]);
  }
}

// ---------------- edge1: ONE 64-thread block per dst node; epilogue fuses b1+relu+W2 -> P2 ----------------
__global__ __launch_bounds__(64) void k_edge1(const u16* __restrict__ Hh16, const float* __restrict__ ES,
                                              const float* __restrict__ ED, const int* __restrict__ rowptr,
                                              const int* __restrict__ ssrc, const float* __restrict__ b1,
                                              const float* __restrict__ W2,
                                              const float* __restrict__ as2, const float* __restrict__ ad2,
                                              float* __restrict__ P2, int N){
  __shared__ int   ssh[64];
  __shared__ float wsh[4][68];
  int lane = threadIdx.x;
  int n = blockIdx.x;
  int myhead = lane & 3;                 // permuted layout: lane covers cols 64(l&3)+16j+(l>>2)
  int start = rowptr[n], deg = rowptr[n + 1] - start;
  float4 ed4 = ((const float4*)ED)[n];

  float accv[4] = {0.f, 0.f, 0.f, 0.f};
  float4 den = make_float4(0.f,0.f,0.f,0.f);

  for (int base = 0; base < deg; base += 64){
    int i = base + lane;
    float4 wt = make_float4(0.f,0.f,0.f,0.f);
    int s = 0;
    if (i < deg){
      s = ssrc[start + i];
      float4 e = ((const float4*)ES)[s];
      e.x += ed4.x; e.y += ed4.y; e.z += ed4.z; e.w += ed4.w;
      e.x = fmaxf(e.x, 0.2f*e.x); e.y = fmaxf(e.y, 0.2f*e.y);
      e.z = fmaxf(e.z, 0.2f*e.z); e.w = fmaxf(e.w, 0.2f*e.w);
      wt.x = __expf(e.x); wt.y = __expf(e.y);
      wt.z = __expf(e.z); wt.w = __expf(e.w);
    }
    den.x += wt.x; den.y += wt.y; den.z += wt.z; den.w += wt.w;
    ssh[lane] = s;
    wsh[0][lane] = wt.x; wsh[1][lane] = wt.y;
    wsh[2][lane] = wt.z; wsh[3][lane] = wt.w;
    __syncthreads();
    agg_rows16(Hh16, ssh, wsh[myhead], min(deg - base, 64), lane, accv);
    __syncthreads();
  }

  wred_sum4(den);
  float d = (myhead==0)?den.x:(myhead==1)?den.y:(myhead==2)?den.z:den.w;
  float inv = 1.f / (d + 1e-16f);
  int c0 = 64 * (lane & 3) + (lane >> 2);   // col_j = c0 + 16j
  float p0 = 0.f, p1 = 0.f;
  #pragma unroll
  for (int j = 0; j < 4; j++){
    int col = c0 + 16 * j;
    float v = fmaxf(fmaf(accv[j], inv, b1[col]), 0.f);
    float2 w2 = ((const float2*)W2)[col];
    p0 = fmaf(v, w2.x, p0);
    p1 = fmaf(v, w2.y, p1);
  }
  p0 = wred_sum(p0); p1 = wred_sum(p1);
  if (lane == 0){
    float4 o;
    o.x = p0; o.y = p1;
    o.z = p0*as2[0] + p1*as2[1];
    o.w = p0*ad2[0] + p1*ad2[1];
    ((float4*)P2)[n] = o;
  }
}

// ---------------- edge2: H=1, O=2; P2 = {h2a,h2b,es2,ed2}; single pass ----------------
__global__ __launch_bounds__(256) void k_edge2(const float* __restrict__ P2, const int* __restrict__ rowptr,
                                               const int* __restrict__ ssrc, const float* __restrict__ bias,
                                               float* __restrict__ Out, int N){
  int lane = threadIdx.x & 63;
  int n = blockIdx.x * 4 + (threadIdx.x >> 6);
  if (n >= N) return;
  int start = rowptr[n], deg = rowptr[n + 1] - start;
  float edn = ((const float4*)P2)[n].w;
  float den = 0.f, a0 = 0.f, a1 = 0.f;
  for (int i = lane; i < deg; i += 64){
    int s = ssrc[start + i];
    float4 p = ((const float4*)P2)[s];
    float a = p.z + edn; a = fmaxf(a, 0.2f * a);
    float w = __expf(a);
    den += w;
    a0 = fmaf(w, p.x, a0);
    a1 = fmaf(w, p.y, a1);
  }
  den = wred_sum(den); a0 = wred_sum(a0); a1 = wred_sum(a1);
  if (lane == 0){
    float inv = 1.f / (den + 1e-16f);
    Out[n*2]     = fmaxf(a0 * inv + bias[0], 0.f);
    Out[n*2 + 1] = fmaxf(a1 * inv + bias[1], 0.f);
  }
}

extern "C" void kernel_launch(void* const* d_in, const int* in_sizes, int n_in,
                              void* d_out, int out_size, void* d_ws, size_t ws_size,
                              hipStream_t stream) {
  const float* x   = (const float*)d_in[0];
  const int*   ei  = (const int*)  d_in[1];
  const float* W0  = (const float*)d_in[2];
  const float* as0 = (const float*)d_in[3];
  const float* ad0 = (const float*)d_in[4];
  const float* b0  = (const float*)d_in[5];
  const float* W1  = (const float*)d_in[6];
  const float* as1 = (const float*)d_in[7];
  const float* ad1 = (const float*)d_in[8];
  const float* b1  = (const float*)d_in[9];
  const float* W2  = (const float*)d_in[10];
  const float* as2 = (const float*)d_in[11];
  const float* ad2 = (const float*)d_in[12];
  const float* b2  = (const float*)d_in[13];

  int N = in_sizes[0] / 2;
  int E = in_sizes[1] / 2;
  const int* src = ei;
  const int* dst = ei + E;

  char* ws = (char*)d_ws;
  size_t off = 0;
  auto alc = [&](size_t bytes){ size_t o = off; off += (bytes + 255) & ~(size_t)255; return o; };
  int*   deg    = (int*)(ws + alc((size_t)N * 4));
  int*   rowptr = (int*)(ws + alc((size_t)(N + 1) * 4));
  int*   cursor = (int*)(ws + alc((size_t)N * 4));
  int*   ssrc   = (int*)(ws + alc((size_t)(E + N) * 4));
  u16*   Hh16   = (u16*)  (ws + alc((size_t)N * 256 * 2));
  float* es1    = (float*)(ws + alc((size_t)N * 4 * 4));
  float* ed1    = (float*)(ws + alc((size_t)N * 4 * 4));
  float* P2     = (float*)(ws + alc((size_t)N * 4 * 4));
  u16*   wht    = (u16*)  (ws + alc((size_t)256 * 256 * 2));
  u16*   wlt    = (u16*)  (ws + alc((size_t)256 * 256 * 2));
  float* vs     = (float*)(ws + alc(16 * 4));
  int*   bsum   = (int*)(ws + alc(64 * 4));
  float* out    = (float*)d_out;

  int nhist  = (E + 255) / 256;
  int nblk_n = (N + 255) / 256;
  int nb     = (N + 2047) / 2048;    // scan blocks (<=64)

  hipMemsetAsync(deg, 0, (size_t)N * 4, stream);
  k_prep      <<<nhist + 257, 256, 0, stream>>>(dst, E, deg, W1, wht, wlt, W0, as0, ad0, vs, nhist);
  k_scan_local<<<nb, 256, 0, stream>>>(deg, rowptr, bsum, N);
  k_finish    <<<nblk_n, 256, 0, stream>>>(rowptr, bsum, ssrc, cursor, N, nb);
  k_scatter   <<<nhist, 256, 0, stream>>>(src, dst, E, cursor, ssrc);

  k_l1f  <<<(N + 127)/128, 512, 0, stream>>>(x, vs, rowptr, ssrc, W0, b0, wht, wlt,
                                             as1, ad1, Hh16, es1, ed1, N);
  k_edge1<<<N, 64, 0, stream>>>(Hh16, es1, ed1, rowptr, ssrc, b1, W2, as2, ad2, P2, N);
  k_edge2<<<(N + 3)/4, 256, 0, stream>>>(P2, rowptr, ssrc, b2, out, N);
}

// Round 12
// 337.805 us; speedup vs baseline: 1.0364x; 1.0364x over previous
//
#include <hip/hip_runtime.h>
#include <math.h>

// 3-layer GAT, N=50000, E=800000 (+N self loops).
// L0 collapsed to 2-dim aggregation -> agg2[N][8]; L1 GEMM reconstructs x1 rows
// from agg2 (rank-2 + bias + relu), split-bf16 MFMA; h1 stored fp16 permuted;
// L2 projection fused into edge1 epilogue. Softmax without max subtraction.
// edge1 gathers 16B/lane with paired-edge halves (even/odd edges per wave half).

typedef __attribute__((ext_vector_type(8))) short s16x8;
typedef __attribute__((ext_vector_type(4))) float f32x4;
typedef unsigned short u16;

__device__ __forceinline__ float wred_sum(float v){
  #pragma unroll
  for (int m = 32; m > 0; m >>= 1) v += __shfl_xor(v, m, 64);
  return v;
}
__device__ __forceinline__ void wred_sum4(float4& v){
  #pragma unroll
  for (int m = 32; m > 0; m >>= 1){
    v.x += __shfl_xor(v.x, m, 64);
    v.y += __shfl_xor(v.y, m, 64);
    v.z += __shfl_xor(v.z, m, 64);
    v.w += __shfl_xor(v.w, m, 64);
  }
}
__device__ __forceinline__ u16 bf16_rne(float x){
  unsigned int u = __float_as_uint(x);
  unsigned int r = u + 0x7FFFu + ((u >> 16) & 1u);
  return (u16)(r >> 16);
}

// ---------------- prep: edge histogram + W1 hi/lo transpose-convert + vs(=W0@a0) ----------------
__global__ __launch_bounds__(256) void k_prep(const int* __restrict__ dst, int E, int* __restrict__ deg,
                                              const float* __restrict__ W1, u16* __restrict__ WhT,
                                              u16* __restrict__ WlT,
                                              const float* __restrict__ W0, const float* __restrict__ as0,
                                              const float* __restrict__ ad0, float* __restrict__ vs,
                                              int nhist){
  int b = blockIdx.x;
  if (b < nhist){
    int e = b * 256 + threadIdx.x;
    if (e < E) atomicAdd(&deg[dst[e]], 1);
  } else if (b < nhist + 256){
    int k = b - nhist, j = threadIdx.x;
    float w = W1[k * 256 + j];
    u16 h = bf16_rne(w);
    float hf = __uint_as_float(((unsigned int)h) << 16);
    WhT[j * 256 + k] = h;
    WlT[j * 256 + k] = bf16_rne(w - hf);
  } else {
    int t = threadIdx.x;
    if (t < 8){
      int j = t >> 2, h = t & 3;
      float ss = 0.f, dd = 0.f;
      #pragma unroll 8
      for (int o = 0; o < 64; o++){
        float w = W0[j * 256 + h * 64 + o];
        ss = fmaf(w, as0[h * 64 + o], ss);
        dd = fmaf(w, ad0[h * 64 + o], dd);
      }
      vs[j * 4 + h]     = ss;   // src proj
      vs[8 + j * 4 + h] = dd;   // dst proj
    }
  }
}

// ---------------- scan: local (2048/block, deg+1 for self loop) -> finish ----------------
__global__ __launch_bounds__(256) void k_scan_local(const int* __restrict__ deg, int* __restrict__ rowptr,
                                                    int* __restrict__ bsum, int N){
  __shared__ int sb[256];
  int t = threadIdx.x;
  int base = blockIdx.x * 2048 + t * 8;
  int d[8], s = 0;
  #pragma unroll
  for (int k = 0; k < 8; k++){
    d[k] = (base + k < N) ? (deg[base + k] + 1) : 0;
    s += d[k];
  }
  sb[t] = s;
  __syncthreads();
  for (int off = 1; off < 256; off <<= 1){
    int v = (t >= off) ? sb[t - off] : 0;
    __syncthreads();
    sb[t] += v;
    __syncthreads();
  }
  int run = (t == 0) ? 0 : sb[t - 1];
  #pragma unroll
  for (int k = 0; k < 8; k++){
    if (base + k < N) rowptr[base + k] = run;
    run += d[k];
  }
  if (t == 255) bsum[blockIdx.x] = sb[255];
}

__global__ __launch_bounds__(256) void k_finish(int* __restrict__ rowptr, const int* __restrict__ bsum,
                                                int* __restrict__ ssrc, int* __restrict__ cursor,
                                                int N, int nb){
  __shared__ int off_sh;
  int i = blockIdx.x * 256 + threadIdx.x;
  if (threadIdx.x == 0){
    int bk = blockIdx.x >> 3;     // 256-range never crosses a 2048 boundary
    int s = 0;
    for (int k = 0; k < bk; k++) s += bsum[k];
    off_sh = s;
  }
  __syncthreads();
  if (i < N){
    int p = rowptr[i] + off_sh;
    rowptr[i] = p;
    ssrc[p] = i;          // self loop first in segment
    cursor[i] = p + 1;
  }
  if (i == 0){
    int s = 0;
    for (int k = 0; k < nb; k++) s += bsum[k];
    rowptr[N] = s;
  }
}

__global__ __launch_bounds__(256) void k_scatter(const int* __restrict__ src, const int* __restrict__ dst,
                                                 int E, int* cursor, int* ssrc){
  int e = blockIdx.x * 256 + threadIdx.x;
  if (e < E){ int p = atomicAdd(&cursor[dst[e]], 1); ssrc[p] = src[e]; }
}

// ---------------- edge0: 2-dim aggregation, single pass; writes agg2[N][8] ----------------
__global__ __launch_bounds__(256) void k_edge0(const float* __restrict__ X, const float* __restrict__ vs,
                                               const int* __restrict__ rowptr, const int* __restrict__ ssrc,
                                               float* __restrict__ agg2, int N){
  int lane = threadIdx.x & 63;
  int n = blockIdx.x * 4 + (threadIdx.x >> 6);
  if (n >= N) return;
  int start = rowptr[n], deg = rowptr[n + 1] - start;
  float4 va = ((const float4*)vs)[0], vb = ((const float4*)vs)[1];
  float4 vc = ((const float4*)vs)[2], vd = ((const float4*)vs)[3];
  float2 xn = ((const float2*)X)[n];
  float4 ed4;
  ed4.x = fmaf(xn.x, vc.x, xn.y * vd.x); ed4.y = fmaf(xn.x, vc.y, xn.y * vd.y);
  ed4.z = fmaf(xn.x, vc.z, xn.y * vd.z); ed4.w = fmaf(xn.x, vc.w, xn.y * vd.w);

  float4 den = make_float4(0.f,0.f,0.f,0.f);
  float4 a0  = make_float4(0.f,0.f,0.f,0.f);
  float4 a1  = make_float4(0.f,0.f,0.f,0.f);
  for (int i = lane; i < deg; i += 64){
    int s = ssrc[start + i];
    float2 xs = ((const float2*)X)[s];
    float4 e;
    e.x = fmaf(xs.x, va.x, fmaf(xs.y, vb.x, ed4.x));
    e.y = fmaf(xs.x, va.y, fmaf(xs.y, vb.y, ed4.y));
    e.z = fmaf(xs.x, va.z, fmaf(xs.y, vb.z, ed4.z));
    e.w = fmaf(xs.x, va.w, fmaf(xs.y, vb.w, ed4.w));
    e.x = fmaxf(e.x, 0.2f*e.x); e.y = fmaxf(e.y, 0.2f*e.y);
    e.z = fmaxf(e.z, 0.2f*e.z); e.w = fmaxf(e.w, 0.2f*e.w);
    float4 wt;
    wt.x = __expf(e.x); wt.y = __expf(e.y);
    wt.z = __expf(e.z); wt.w = __expf(e.w);
    den.x += wt.x; den.y += wt.y; den.z += wt.z; den.w += wt.w;
    a0.x = fmaf(wt.x, xs.x, a0.x); a0.y = fmaf(wt.y, xs.x, a0.y);
    a0.z = fmaf(wt.z, xs.x, a0.z); a0.w = fmaf(wt.w, xs.x, a0.w);
    a1.x = fmaf(wt.x, xs.y, a1.x); a1.y = fmaf(wt.y, xs.y, a1.y);
    a1.z = fmaf(wt.z, xs.y, a1.z); a1.w = fmaf(wt.w, xs.y, a1.w);
  }
  wred_sum4(den); wred_sum4(a0); wred_sum4(a1);

  if (lane == 0){
    float4 inv;
    inv.x = 1.f / (den.x + 1e-16f); inv.y = 1.f / (den.y + 1e-16f);
    inv.z = 1.f / (den.z + 1e-16f); inv.w = 1.f / (den.w + 1e-16f);
    float4 gA, gB;                              // {h0g0,h0g1,h1g0,h1g1}, {h2g0,...}
    gA.x = a0.x * inv.x; gA.y = a1.x * inv.x;
    gA.z = a0.y * inv.y; gA.w = a1.y * inv.y;
    gB.x = a0.z * inv.z; gB.y = a1.z * inv.z;
    gB.z = a0.w * inv.w; gB.w = a1.w * inv.w;
    float4* g = (float4*)(agg2 + (size_t)n * 8);
    g[0] = gA; g[1] = gB;
  }
}

// ---------------- L1 GEMM: x1 reconstructed from agg2; h1 -> fp16 permuted; ES1/ED1 epilogue ----------------
// x1[n][c] = relu(g0(h)*W0[0][c] + g1(h)*W0[1][c] + b0[c]), h = c>>6.
// Permuted row layout: position p = lr*16 + c holds column c*16 + lr.
__global__ __launch_bounds__(256) void k_l1_mfma(const float* __restrict__ agg2,
                                                 const float* __restrict__ W0, const float* __restrict__ b0,
                                                 const u16* __restrict__ WhT, const u16* __restrict__ WlT,
                                                 const float* __restrict__ as_, const float* __restrict__ ad_,
                                                 u16* __restrict__ Hh16, float* __restrict__ ES,
                                                 float* __restrict__ ED, int N){
  __shared__ u16 Ah[64 * 32], Al[64 * 32];
  __shared__ u16 Bh[256 * 32], Bl[256 * 32];
  int t = threadIdx.x;
  int wv = t >> 6, lane = t & 63;
  int lr = lane & 15, lg = lane >> 4;
  int rb = blockIdx.x * 64;

  f32x4 acc[16];
  #pragma unroll
  for (int c = 0; c < 16; c++) acc[c] = (f32x4){0.f, 0.f, 0.f, 0.f};

  int arow = t >> 2, aseg = t & 3;
  int agrow = rb + arow;
  float4 ga = make_float4(0.f,0.f,0.f,0.f), gb = make_float4(0.f,0.f,0.f,0.f);
  if (agrow < N){
    const float4* g = (const float4*)(agg2 + (size_t)agrow * 8);
    ga = g[0]; gb = g[1];
  }

  for (int ks = 0; ks < 8; ks++){
    int k0 = ks * 32;
    __syncthreads();
    {
      int c0 = k0 + aseg * 8;
      int h = c0 >> 6;
      float g0 = (h==0)?ga.x:(h==1)?ga.z:(h==2)?gb.x:gb.z;
      float g1 = (h==0)?ga.y:(h==1)?ga.w:(h==2)?gb.y:gb.w;
      float4 w0a = *(const float4*)(W0 + c0);
      float4 w0b = *(const float4*)(W0 + c0 + 4);
      float4 w1a = *(const float4*)(W0 + 256 + c0);
      float4 w1b = *(const float4*)(W0 + 256 + c0 + 4);
      float4 bba = *(const float4*)(b0 + c0);
      float4 bbb = *(const float4*)(b0 + c0 + 4);
      float xv[8];
      xv[0] = fmaxf(fmaf(g0, w0a.x, fmaf(g1, w1a.x, bba.x)), 0.f);
      xv[1] = fmaxf(fmaf(g0, w0a.y, fmaf(g1, w1a.y, bba.y)), 0.f);
      xv[2] = fmaxf(fmaf(g0, w0a.z, fmaf(g1, w1a.z, bba.z)), 0.f);
      xv[3] = fmaxf(fmaf(g0, w0a.w, fmaf(g1, w1a.w, bba.w)), 0.f);
      xv[4] = fmaxf(fmaf(g0, w0b.x, fmaf(g1, w1b.x, bbb.x)), 0.f);
      xv[5] = fmaxf(fmaf(g0, w0b.y, fmaf(g1, w1b.y, bbb.y)), 0.f);
      xv[6] = fmaxf(fmaf(g0, w0b.z, fmaf(g1, w1b.z, bbb.z)), 0.f);
      xv[7] = fmaxf(fmaf(g0, w0b.w, fmaf(g1, w1b.w, bbb.w)), 0.f);
      if (agrow >= N){
        #pragma unroll
        for (int i = 0; i < 8; i++) xv[i] = 0.f;
      }
      union { u16 us[8]; uint4 v; } ph, pl;
      #pragma unroll
      for (int i = 0; i < 8; i++){
        u16 h16 = bf16_rne(xv[i]);
        float hf = __uint_as_float(((unsigned int)h16) << 16);
        ph.us[i] = h16;
        pl.us[i] = bf16_rne(xv[i] - hf);
      }
      *(uint4*)&Ah[arow * 32 + aseg * 8] = ph.v;
      *(uint4*)&Al[arow * 32 + aseg * 8] = pl.v;
    }
    #pragma unroll
    for (int i = 0; i < 4; i++){
      int chunk = i * 256 + t;
      int j = chunk >> 2, seg = chunk & 3;
      *(uint4*)&Bh[j * 32 + seg * 8] = *(const uint4*)&WhT[j * 256 + k0 + seg * 8];
      *(uint4*)&Bl[j * 32 + seg * 8] = *(const uint4*)&WlT[j * 256 + k0 + seg * 8];
    }
    __syncthreads();
    s16x8 ah = *(const s16x8*)&Ah[(wv * 16 + lr) * 32 + lg * 8];
    s16x8 al = *(const s16x8*)&Al[(wv * 16 + lr) * 32 + lg * 8];
    #pragma unroll
    for (int c = 0; c < 16; c++){
      s16x8 bh = *(const s16x8*)&Bh[(c * 16 + lr) * 32 + lg * 8];
      s16x8 bl = *(const s16x8*)&Bl[(c * 16 + lr) * 32 + lg * 8];
      acc[c] = __builtin_amdgcn_mfma_f32_16x16x32_bf16(ah, bh, acc[c], 0, 0, 0);
      acc[c] = __builtin_amdgcn_mfma_f32_16x16x32_bf16(ah, bl, acc[c], 0, 0, 0);
      acc[c] = __builtin_amdgcn_mfma_f32_16x16x32_bf16(al, bh, acc[c], 0, 0, 0);
    }
  }

  // fp16 permuted write: row n, positions lr*16 + c (c=0..15) = cols c*16+lr
  #pragma unroll
  for (int q = 0; q < 4; q++){
    int n = rb + wv * 16 + lg * 4 + q;
    if (n < N){
      union { _Float16 h[16]; uint4 v[2]; } pk;
      #pragma unroll
      for (int c = 0; c < 16; c++) pk.h[c] = (_Float16)acc[c][q];
      uint4* dstp = (uint4*)(Hh16 + (size_t)n * 256 + lr * 16);
      dstp[0] = pk.v[0];
      dstp[1] = pk.v[1];
    }
  }
  // ES1/ED1 from full f32 acc
  float es_p[4][4], ed_p[4][4];
  #pragma unroll
  for (int h = 0; h < 4; h++)
    #pragma unroll
    for (int q = 0; q < 4; q++){ es_p[h][q] = 0.f; ed_p[h][q] = 0.f; }
  #pragma unroll
  for (int c = 0; c < 16; c++){
    float asv = as_[c * 16 + lr];
    float adv = ad_[c * 16 + lr];
    int h = c >> 2;
    #pragma unroll
    for (int q = 0; q < 4; q++){
      es_p[h][q] = fmaf(acc[c][q], asv, es_p[h][q]);
      ed_p[h][q] = fmaf(acc[c][q], adv, ed_p[h][q]);
    }
  }
  #pragma unroll
  for (int h = 0; h < 4; h++)
    #pragma unroll
    for (int q = 0; q < 4; q++){
      #pragma unroll
      for (int mk = 1; mk < 16; mk <<= 1){
        es_p[h][q] += __shfl_xor(es_p[h][q], mk, 64);
        ed_p[h][q] += __shfl_xor(ed_p[h][q], mk, 64);
      }
    }
  if (lr == 0){
    #pragma unroll
    for (int q = 0; q < 4; q++){
      int n = rb + wv * 16 + lg * 4 + q;
      if (n < N){
        #pragma unroll
        for (int h = 0; h < 4; h++){
          ES[n * 4 + h] = es_p[h][q];
          ED[n * 4 + h] = ed_p[h][q];
        }
      }
    }
  }
}

// ---------------- edge1: ONE 64-thread block per dst node; 16B paired-edge gather ----------------
// Lane halves: lanes 0-31 handle even edges, 32-63 odd edges; each lane loads 16B
// (positions 8*l32 .. 8*l32+7 of the permuted fp16 row). head(k) = 2*(l32&1) + (k>>2).
__global__ __launch_bounds__(64) void k_edge1(const u16* __restrict__ Hh16, const float* __restrict__ ES,
                                              const float* __restrict__ ED, const int* __restrict__ rowptr,
                                              const int* __restrict__ ssrc, const float* __restrict__ b1,
                                              const float* __restrict__ W2,
                                              const float* __restrict__ as2, const float* __restrict__ ad2,
                                              float* __restrict__ P2, int N){
  __shared__ int   ssh[64];
  __shared__ float wsh[4][68];
  int lane = threadIdx.x;
  int n = blockIdx.x;
  int start = rowptr[n], deg = rowptr[n + 1] - start;
  float4 ed4 = ((const float4*)ED)[n];

  int half = lane >> 5;
  int l32  = lane & 31;
  int hA = 2 * (l32 & 1);
  int hB = hA + 1;
  const u16* rowbase = Hh16 + 8 * l32;   // +s*256 per edge

  float acc8[8] = {0.f,0.f,0.f,0.f,0.f,0.f,0.f,0.f};
  float4 den = make_float4(0.f,0.f,0.f,0.f);
  union Cv { uint4 v; _Float16 h[8]; };

  for (int base = 0; base < deg; base += 64){
    int i = base + lane;
    float4 wt = make_float4(0.f,0.f,0.f,0.f);
    int s = 0;
    if (i < deg){
      s = ssrc[start + i];
      float4 e = ((const float4*)ES)[s];
      e.x += ed4.x; e.y += ed4.y; e.z += ed4.z; e.w += ed4.w;
      e.x = fmaxf(e.x, 0.2f*e.x); e.y = fmaxf(e.y, 0.2f*e.y);
      e.z = fmaxf(e.z, 0.2f*e.z); e.w = fmaxf(e.w, 0.2f*e.w);
      wt.x = __expf(e.x); wt.y = __expf(e.y);
      wt.z = __expf(e.z); wt.w = __expf(e.w);
    }
    den.x += wt.x; den.y += wt.y; den.z += wt.z; den.w += wt.w;
    ssh[lane] = s;
    wsh[0][lane] = wt.x; wsh[1][lane] = wt.y;
    wsh[2][lane] = wt.z; wsh[3][lane] = wt.w;
    __syncthreads();
    int cl = min(deg - base, 64);
    const float* wrA = wsh[hA];
    const float* wrB = wsh[hB];
    int j = half;
    for (; j + 14 < cl; j += 16){
      int s0=ssh[j],s1=ssh[j+2],s2=ssh[j+4],s3=ssh[j+6];
      int s4=ssh[j+8],s5=ssh[j+10],s6=ssh[j+12],s7=ssh[j+14];
      float wa0=wrA[j],wb0=wrB[j],wa1=wrA[j+2],wb1=wrB[j+2];
      float wa2=wrA[j+4],wb2=wrB[j+4],wa3=wrA[j+6],wb3=wrB[j+6];
      float wa4=wrA[j+8],wb4=wrB[j+8],wa5=wrA[j+10],wb5=wrB[j+10];
      float wa6=wrA[j+12],wb6=wrB[j+12],wa7=wrA[j+14],wb7=wrB[j+14];
      Cv r0,r1,r2,r3,r4,r5,r6,r7;
      r0.v = *(const uint4*)(rowbase + (size_t)s0*256);
      r1.v = *(const uint4*)(rowbase + (size_t)s1*256);
      r2.v = *(const uint4*)(rowbase + (size_t)s2*256);
      r3.v = *(const uint4*)(rowbase + (size_t)s3*256);
      r4.v = *(const uint4*)(rowbase + (size_t)s4*256);
      r5.v = *(const uint4*)(rowbase + (size_t)s5*256);
      r6.v = *(const uint4*)(rowbase + (size_t)s6*256);
      r7.v = *(const uint4*)(rowbase + (size_t)s7*256);
      #pragma unroll
      for (int k = 0; k < 4; k++) acc8[k] = fmaf(wa0, (float)r0.h[k], acc8[k]);
      #pragma unroll
      for (int k = 4; k < 8; k++) acc8[k] = fmaf(wb0, (float)r0.h[k], acc8[k]);
      #pragma unroll
      for (int k = 0; k < 4; k++) acc8[k] = fmaf(wa1, (float)r1.h[k], acc8[k]);
      #pragma unroll
      for (int k = 4; k < 8; k++) acc8[k] = fmaf(wb1, (float)r1.h[k], acc8[k]);
      #pragma unroll
      for (int k = 0; k < 4; k++) acc8[k] = fmaf(wa2, (float)r2.h[k], acc8[k]);
      #pragma unroll
      for (int k = 4; k < 8; k++) acc8[k] = fmaf(wb2, (float)r2.h[k], acc8[k]);
      #pragma unroll
      for (int k = 0; k < 4; k++) acc8[k] = fmaf(wa3, (float)r3.h[k], acc8[k]);
      #pragma unroll
      for (int k = 4; k < 8; k++) acc8[k] = fmaf(wb3, (float)r3.h[k], acc8[k]);
      #pragma unroll
      for (int k = 0; k < 4; k++) acc8[k] = fmaf(wa4, (float)r4.h[k], acc8[k]);
      #pragma unroll
      for (int k = 4; k < 8; k++) acc8[k] = fmaf(wb4, (float)r4.h[k], acc8[k]);
      #pragma unroll
      for (int k = 0; k < 4; k++) acc8[k] = fmaf(wa5, (float)r5.h[k], acc8[k]);
      #pragma unroll
      for (int k = 4; k < 8; k++) acc8[k] = fmaf(wb5, (float)r5.h[k], acc8[k]);
      #pragma unroll
      for (int k = 0; k < 4; k++) acc8[k] = fmaf(wa6, (float)r6.h[k], acc8[k]);
      #pragma unroll
      for (int k = 4; k < 8; k++) acc8[k] = fmaf(wb6, (float)r6.h[k], acc8[k]);
      #pragma unroll
      for (int k = 0; k < 4; k++) acc8[k] = fmaf(wa7, (float)r7.h[k], acc8[k]);
      #pragma unroll
      for (int k = 4; k < 8; k++) acc8[k] = fmaf(wb7, (float)r7.h[k], acc8[k]);
    }
    for (; j < cl; j += 2){
      int s0 = ssh[j];
      float wa = wrA[j], wb = wrB[j];
      Cv r;
      r.v = *(const uint4*)(rowbase + (size_t)s0*256);
      #pragma unroll
      for (int k = 0; k < 4; k++) acc8[k] = fmaf(wa, (float)r.h[k], acc8[k]);
      #pragma unroll
      for (int k = 4; k < 8; k++) acc8[k] = fmaf(wb, (float)r.h[k], acc8[k]);
    }
    __syncthreads();
  }

  // combine even/odd halves (same positions in both halves)
  #pragma unroll
  for (int k = 0; k < 8; k++) acc8[k] += __shfl_xor(acc8[k], 32, 64);
  wred_sum4(den);
  float invA = 1.f / (((hA == 0) ? den.x : den.z) + 1e-16f);
  float invB = 1.f / (((hB == 1) ? den.y : den.w) + 1e-16f);

  float p0 = 0.f, p1 = 0.f;
  if (half == 0){
    #pragma unroll
    for (int k = 0; k < 8; k++){
      int p = 8 * l32 + k;
      int col = (p & 15) * 16 + (p >> 4);
      float inv = (k < 4) ? invA : invB;
      float v = fmaxf(fmaf(acc8[k], inv, b1[col]), 0.f);
      float2 w2 = ((const float2*)W2)[col];
      p0 = fmaf(v, w2.x, p0);
      p1 = fmaf(v, w2.y, p1);
    }
  }
  p0 = wred_sum(p0); p1 = wred_sum(p1);
  if (lane == 0){
    float4 o;
    o.x = p0; o.y = p1;
    o.z = p0*as2[0] + p1*as2[1];
    o.w = p0*ad2[0] + p1*ad2[1];
    ((float4*)P2)[n] = o;
  }
}

// ---------------- edge2: H=1, O=2; P2 = {h2a,h2b,es2,ed2}; single pass ----------------
__global__ __launch_bounds__(256) void k_edge2(const float* __restrict__ P2, const int* __restrict__ rowptr,
                                               const int* __restrict__ ssrc, const float* __restrict__ bias,
                                               float* __restrict__ Out, int N){
  int lane = threadIdx.x & 63;
  int n = blockIdx.x * 4 + (threadIdx.x >> 6);
  if (n >= N) return;
  int start = rowptr[n], deg = rowptr[n + 1] - start;
  float edn = ((const float4*)P2)[n].w;
  float den = 0.f, a0 = 0.f, a1 = 0.f;
  for (int i = lane; i < deg; i += 64){
    int s = ssrc[start + i];
    float4 p = ((const float4*)P2)[s];
    float a = p.z + edn; a = fmaxf(a, 0.2f * a);
    float w = __expf(a);
    den += w;
    a0 = fmaf(w, p.x, a0);
    a1 = fmaf(w, p.y, a1);
  }
  den = wred_sum(den); a0 = wred_sum(a0); a1 = wred_sum(a1);
  if (lane == 0){
    float inv = 1.f / (den + 1e-16f);
    Out[n*2]     = fmaxf(a0 * inv + bias[0], 0.f);
    Out[n*2 + 1] = fmaxf(a1 * inv + bias[1], 0.f);
  }
}

extern "C" void kernel_launch(void* const* d_in, const int* in_sizes, int n_in,
                              void* d_out, int out_size, void* d_ws, size_t ws_size,
                              hipStream_t stream) {
  const float* x   = (const float*)d_in[0];
  const int*   ei  = (const int*)  d_in[1];
  const float* W0  = (const float*)d_in[2];
  const float* as0 = (const float*)d_in[3];
  const float* ad0 = (const float*)d_in[4];
  const float* b0  = (const float*)d_in[5];
  const float* W1  = (const float*)d_in[6];
  const float* as1 = (const float*)d_in[7];
  const float* ad1 = (const float*)d_in[8];
  const float* b1  = (const float*)d_in[9];
  const float* W2  = (const float*)d_in[10];
  const float* as2 = (const float*)d_in[11];
  const float* ad2 = (const float*)d_in[12];
  const float* b2  = (const float*)d_in[13];

  int N = in_sizes[0] / 2;
  int E = in_sizes[1] / 2;
  const int* src = ei;
  const int* dst = ei + E;

  char* ws = (char*)d_ws;
  size_t off = 0;
  auto alc = [&](size_t bytes){ size_t o = off; off += (bytes + 255) & ~(size_t)255; return o; };
  int*   deg    = (int*)(ws + alc((size_t)N * 4));
  int*   rowptr = (int*)(ws + alc((size_t)(N + 1) * 4));
  int*   cursor = (int*)(ws + alc((size_t)N * 4));
  int*   ssrc   = (int*)(ws + alc((size_t)(E + N) * 4));
  u16*   Hh16   = (u16*)  (ws + alc((size_t)N * 256 * 2));
  float* agg2   = (float*)(ws + alc((size_t)N * 8 * 4));
  float* es1    = (float*)(ws + alc((size_t)N * 4 * 4));
  float* ed1    = (float*)(ws + alc((size_t)N * 4 * 4));
  float* P2     = (float*)(ws + alc((size_t)N * 4 * 4));
  u16*   wht    = (u16*)  (ws + alc((size_t)256 * 256 * 2));
  u16*   wlt    = (u16*)  (ws + alc((size_t)256 * 256 * 2));
  float* vs     = (float*)(ws + alc(16 * 4));
  int*   bsum   = (int*)(ws + alc(64 * 4));
  float* out    = (float*)d_out;

  int nhist  = (E + 255) / 256;
  int nblk_n = (N + 255) / 256;
  int nb     = (N + 2047) / 2048;    // scan blocks (<=64)

  hipMemsetAsync(deg, 0, (size_t)N * 4, stream);
  k_prep      <<<nhist + 257, 256, 0, stream>>>(dst, E, deg, W1, wht, wlt, W0, as0, ad0, vs, nhist);
  k_scan_local<<<nb, 256, 0, stream>>>(deg, rowptr, bsum, N);
  k_finish    <<<nblk_n, 256, 0, stream>>>(rowptr, bsum, ssrc, cursor, N, nb);
  k_scatter   <<<nhist, 256, 0, stream>>>(src, dst, E, cursor, ssrc);

  k_edge0  <<<(N + 3)/4, 256, 0, stream>>>(x, vs, rowptr, ssrc, agg2, N);
  k_l1_mfma<<<(N + 63)/64, 256, 0, stream>>>(agg2, W0, b0, wht, wlt, as1, ad1, Hh16, es1, ed1, N);
  k_edge1  <<<N, 64, 0, stream>>>(Hh16, es1, ed1, rowptr, ssrc, b1, W2, as2, ad2, P2, N);
  k_edge2  <<<(N + 3)/4, 256, 0, stream>>>(P2, rowptr, ssrc, b2, out, N);
}